// Round 7
// baseline (299.016 us; speedup 1.0000x reference)
//
#include <hip/hip_runtime.h>
#include <hip/hip_bf16.h>

// Problem constants
#define B_ROWS 16384
#define K_DIM  1024
#define N_INT  1023
#define N_OUT  1000

using s8vec = __attribute__((ext_vector_type(8))) short;   // 8 bf16 (4 VGPRs) MFMA operand
using f32x4 = __attribute__((ext_vector_type(4))) float;   // MFMA accumulator

// Workspace layout (bytes). Total ~105 MB.
static const size_t OFF_XB   = 0;                        // bf16 [16384*1024]; DEAD after gemm<0> -> reused as Spart
static const size_t OFF_W1   = OFF_XB   + 33554432;      // bf16 [1024*1024] (row 1023 = 0)
static const size_t OFF_BIAS = OFF_W1   + 2097152;       // f32  [1024]
static const size_t OFF_PROB = OFF_BIAS + 4096;          // bf16 [16384*1024]; node j at col j+1
static const size_t OFF_PATH = OFF_PROB + 33554432;      // bf16 [16384*1024]
static const size_t OFF_W2   = OFF_PATH + 33554432;      // bf16 [1024*1024] (rows >=1000 = 0)
static const size_t OFF_SG   = OFF_W2   + 2097152;       // f32  [4096]: S1 at [node], S2 at [2048+node]
static const size_t OFF_TKT  = OFF_SG   + 16384;         // u32  [1]: reduce_fin ticket

__device__ __forceinline__ float b2f(ushort u) {
  return __uint_as_float(((unsigned)u) << 16);
}
__device__ __forceinline__ float blo(unsigned u) { return __uint_as_float(u << 16); }
__device__ __forceinline__ float bhi(unsigned u) { return __uint_as_float(u & 0xffff0000u); }
__device__ __forceinline__ ushort f2b(float f) {
  unsigned u = __float_as_uint(f);
  u = u + 0x7FFFu + ((u >> 16) & 1u);   // RNE
  return (ushort)(u >> 16);
}

// async global->LDS, 16B per lane; LDS dest is wave-uniform base + lane*16
__device__ __forceinline__ void load_lds16(const ushort* g, ushort* l) {
  __builtin_amdgcn_global_load_lds((const __attribute__((address_space(1))) void*)g,
                                   (__attribute__((address_space(3))) void*)l,
                                   16, 0, 0);
}

// ---------------- fused converts + state zeroing (one launch, replaces memset) ----------------
__global__ __launch_bounds__(256) void cvt_all(const float4* __restrict__ X,
                                               ushort4* __restrict__ O,
                                               const float* __restrict__ Wi,
                                               const float* __restrict__ Wl,
                                               ushort* __restrict__ W1,
                                               ushort* __restrict__ W2,
                                               float* __restrict__ bias,
                                               float* __restrict__ Sg,
                                               unsigned* __restrict__ ticket) {
  const int b = blockIdx.x;
  if (b < 16384) {
    const int i = b * 256 + threadIdx.x;
    const float4 v = X[i];
    ushort4 o;
    o.x = f2b(v.x); o.y = f2b(v.y); o.z = f2b(v.z); o.w = f2b(v.w);
    O[i] = o;
  } else if (b < 24576) {
    const int idx = (b - 16384) * 256 + threadIdx.x;   // [0, 2*2^20)
    if (idx < (1 << 20)) {
      const int n = idx >> 10, k = idx & 1023;
      const float v = (n < N_INT) ? Wi[n * 1025 + 1 + k] : 0.f;
      W1[idx] = f2b(v);
      if (k == 0) bias[n] = (n < N_INT) ? Wi[n * 1025] : 0.f;
    } else {
      const int j = idx - (1 << 20);
      const int n = j >> 10, k = j & 1023;
      const float v = (n < N_OUT) ? Wl[n * 1024 + k] : 0.f;
      W2[j] = f2b(v);
    }
  } else {                                  // b == 24576: zero Sg + ticket (was hipMemsetAsync)
#pragma unroll
    for (int k = 0; k < 16; ++k) Sg[threadIdx.x + 256 * k] = 0.f;
    if (threadIdx.x == 0) *ticket = 0u;
  }
}

// ---------------- GEMM: C = A[M,K] * Bm[N,K]^T, 128x128 tile, 4 waves ----------------
// Session-best structure (round 6, <58us): T3+T4 2-phase pipeline, LDS double-buffer,
// STAGE(next) at TOP of iter, COUNTED s_waitcnt vmcnt(4), raw s_barrier (no drain),
// chunk swizzle on GLOBAL source + ds_read, (256,5) = 5 blocks/CU, fast sigmoid.
// Grid (bm fast, bn=8): all 8 bn-blocks of an A strip share one XCD's L2.
template <int MODE>
__global__ __launch_bounds__(256, 5) void gemm_bt(const ushort* __restrict__ A,
                                                  const ushort* __restrict__ Bm,
                                                  const float* __restrict__ bias,
                                                  void* __restrict__ outp) {
  __shared__ ushort As[2][4096];   // [buf][128 rows][32 k] bf16, chunk-swizzled
  __shared__ ushort Bs[2][4096];
  const int tid = threadIdx.x;
  const int bm = blockIdx.x, bn = blockIdx.y;
  const int lane = tid & 63, wv = tid >> 6;
  const int wm = wv >> 1, wn = wv & 1;
  const int m16 = lane & 15, q = lane >> 4;
  const int qs = q ^ ((m16 >> 1) & 3);          // read-side chunk swizzle (per-lane const)

  const int r0 = tid >> 2;
  const int qsw = (tid & 3) ^ ((r0 >> 1) & 3);
  const ushort* aG = A  + (size_t)(bm * 128 + r0) * 1024 + qsw * 8;
  const ushort* bG = Bm + (size_t)(bn * 128 + r0) * 1024 + qsw * 8;

  f32x4 acc[4][4] = {};

#define STAGE(buf, kk) do {                                   \
    load_lds16(aG + (kk), As[buf] + wv * 512);                \
    load_lds16(aG + 65536 + (kk), As[buf] + 2048 + wv * 512); \
    load_lds16(bG + (kk), Bs[buf] + wv * 512);                \
    load_lds16(bG + 65536 + (kk), Bs[buf] + 2048 + wv * 512); \
  } while (0)

#define COMPUTE(cur) do {                                                        \
    s8vec af[4], bfv[4];                                                         \
    _Pragma("unroll")                                                            \
    for (int i = 0; i < 4; ++i)                                                  \
      af[i] = *(const s8vec*)(As[cur] + (wm * 64 + i * 16 + m16) * 32 + qs * 8); \
    _Pragma("unroll")                                                            \
    for (int j = 0; j < 4; ++j)                                                  \
      bfv[j] = *(const s8vec*)(Bs[cur] + (wn * 64 + j * 16 + m16) * 32 + qs * 8);\
    _Pragma("unroll")                                                            \
    for (int i = 0; i < 4; ++i)                                                  \
      _Pragma("unroll")                                                          \
      for (int j = 0; j < 4; ++j)                                                \
        acc[i][j] = __builtin_amdgcn_mfma_f32_16x16x32_bf16(af[i], bfv[j],       \
                                                            acc[i][j], 0, 0, 0);\
  } while (0)

  STAGE(0, 0);                                  // prologue: tile 0 in flight
#pragma unroll 1
  for (int k0 = 0; k0 < 992; k0 += 32) {
    const int cur = (k0 >> 5) & 1;
    STAGE(cur ^ 1, k0 + 32);                    // issue next tile (8 loads now in flight)
    asm volatile("s_waitcnt vmcnt(4)\n\ts_barrier" ::: "memory");  // cur landed; next stays in flight
    COMPUTE(cur);
    asm volatile("s_barrier" ::: "memory");     // all waves done reading cur (no drain)
  }
  // epilogue: tile 31 (cur = 1), nothing left to prefetch
  asm volatile("s_waitcnt vmcnt(0)\n\ts_barrier" ::: "memory");
  COMPUTE(1);
#undef STAGE
#undef COMPUTE

  // C/D layout: col = lane&15, row = (lane>>4)*4 + r   [measured: learn_hip m89/m91]
  if (MODE == 0) {
    ushort* P = (ushort*)outp;
#pragma unroll
    for (int i = 0; i < 4; ++i)
#pragma unroll
      for (int r = 0; r < 4; ++r) {
        const int gr = bm * 128 + wm * 64 + i * 16 + q * 4 + r;
#pragma unroll
        for (int j = 0; j < 4; ++j) {
          const int gc = bn * 128 + wn * 64 + j * 16 + m16;
          const float z = acc[i][j][r] + bias[gc];
          const float p = __builtin_amdgcn_rcpf(1.f + __expf(-z));   // fast sigmoid (bf16 out)
          if (gc < N_INT) P[(size_t)gr * 1024 + gc + 1] = f2b(p);  // +1 layer-aligned layout
        }
      }
  } else {
    float* O = (float*)outp;
#pragma unroll
    for (int i = 0; i < 4; ++i)
#pragma unroll
      for (int r = 0; r < 4; ++r) {
        const int gr = bm * 128 + wm * 64 + i * 16 + q * 4 + r;
#pragma unroll
        for (int j = 0; j < 4; ++j) {
          const int gc = bn * 128 + wn * 64 + j * 16 + m16;
          if (gc < N_OUT) O[(size_t)gr * 1000 + gc] = acc[i][j][r];
        }
      }
  }
}

// ---------------- tree: routing + S1/S2 accumulation, SHUFFLE-LEAN ----------------
// 1024 blocks x 4 waves x 4 rows. Round-7 change: all gathered operands (routing
// ancestors, j9/j8/j7/j6 node probs, q-layer probs) were __shfl (ds_bpermute,
// ~40/row, dependent ~50cy LDS chains); every one is literally prow[...] -> now
// DIRECT loads from L1-hot lines (same lines the bulk loads touch). DS ops/row
// drop 40 -> 10 (only the T subtree-sum chain gathers REGISTER data and must stay
// shfl). Routing product is a log-depth tree of 6 independent loads.
__global__ __launch_bounds__(256) void tree_kernel(const ushort* __restrict__ probs,
                                                   ushort* __restrict__ path,
                                                   float* __restrict__ Spart) {
  __shared__ float Ss[2048];    // [0..1023]=S1 by node id, [1024..2047]=S2
  for (int i = threadIdx.x; i < 2048; i += 256) Ss[i] = 0.f;
  __syncthreads();
  const int lane = threadIdx.x & 63;
  const int la = lane & 31;                    // lanes>=32 mirror lane-31 addrs (no OOB)
  const int gw = blockIdx.x * 4 + (threadIdx.x >> 6);   // 4096 waves x 4 rows

  float a19[16] = {}, a29[16] = {};   // layer 9: j = 16*la + i (lane<32)
  float a18[8]  = {}, a28[8]  = {};   // layer 8
  float a17[4]  = {}, a27[4]  = {};   // layer 7
  float a16[2]  = {}, a26[2]  = {};   // layer 6
  float t1[6] = {}, t2[6] = {};       // layers 0..5

#pragma unroll 1
  for (int rr = 0; rr < 4; ++rr) {
    const int r = gw * 4 + rr;
    const ushort* prow = probs + (size_t)r * 1024;

    // ---- bulk per-lane loads (independent; all issue together) ----
    const ushort p6 = prow[64 + lane];
    const uint   p7 = *(const uint*)(prow + 128 + 2 * lane);
    const uint2  p8 = *(const uint2*)(prow + 256 + 4 * lane);
    const uint4  p9 = *(const uint4*)(prow + 512 + 8 * lane);
    // accumulation operands (cache-hot re-reads; replace 30+ bpermutes)
    union { uint4 q[2]; ushort u[16]; } j9;
    j9.q[0] = *(const uint4*)(prow + 512 + 16 * la);
    j9.q[1] = *(const uint4*)(prow + 512 + 16 * la + 8);
    union { uint4 q; ushort u[8]; } j8;
    j8.q = *(const uint4*)(prow + 256 + 8 * la);
    union { uint2 q; ushort u[4]; } j7;
    j7.q = *(const uint2*)(prow + 128 + 4 * la);
    union { uint q; ushort u[2]; } j6;
    j6.q = *(const uint*)(prow + 64 + 2 * la);
    const float q5 = b2f(prow[32 + la]);
    const float q4 = b2f(prow[16 + (lane & 15)]);
    const float q3 = b2f(prow[8 + (lane & 7)]);
    const float q2 = b2f(prow[4 + (lane & 3)]);
    const float q1 = b2f(prow[2 + (lane & 1)]);
    const float q0 = b2f(prow[1]);
    // routing ancestor probs: 6 independent loads within the first 2 cache lines
    float fac[6];
#pragma unroll
    for (int t = 1; t <= 6; ++t) {
      const int ell = t - 1;
      const int e = lane >> (6 - t);
      const float p = b2f(prow[(1 << ell) + (e >> 1)]);   // addr <= 47
      fac[ell] = (e & 1) ? (1.f - p) : p;
    }
    const float v = (fac[0] * fac[1]) * (fac[2] * fac[3]) * (fac[4] * fac[5]);

    // ---- splits (layers 6..9) ----
    float w[16];
    { const float p = b2f(p6); w[1] = v * (1.f - p); w[0] = v * p; }
    {
      const float pA = blo(p7), pB = bhi(p7);
      w[3] = w[1] * (1.f - pB); w[2] = w[1] * pB;
      w[1] = w[0] * (1.f - pA); w[0] = w[0] * pA;
    }
    {
      const float pv[4] = { blo(p8.x), bhi(p8.x), blo(p8.y), bhi(p8.y) };
#pragma unroll
      for (int i = 3; i >= 0; --i) {
        w[2 * i + 1] = w[i] * (1.f - pv[i]);
        w[2 * i]     = w[i] * pv[i];
      }
    }
    {
      const uint pv[4] = { p9.x, p9.y, p9.z, p9.w };
#pragma unroll
      for (int i = 7; i >= 0; --i) {
        const float p = (i & 1) ? bhi(pv[i >> 1]) : blo(pv[i >> 1]);
        w[2 * i + 1] = w[i] * (1.f - p);
        w[2 * i]     = w[i] * p;
      }
    }
    union { ushort u[16]; uint4 q4v[2]; } pk;
#pragma unroll
    for (int i = 0; i < 16; ++i) pk.u[i] = f2b(w[i]);
    uint4* dst = (uint4*)(path + (size_t)r * 1024 + lane * 16);
    dst[0] = pk.q4v[0];
    dst[1] = pk.q4v[1];

    // ---- accumulation from in-register leaves (subtree-sum identity) ----
    float L8[8], L7[4], L6[2];
#pragma unroll
    for (int i = 0; i < 8; ++i) L8[i] = w[2 * i] + w[2 * i + 1];
#pragma unroll
    for (int i = 0; i < 4; ++i) L7[i] = L8[2 * i] + L8[2 * i + 1];
    L6[0] = L7[0] + L7[1]; L6[1] = L7[2] + L7[3];
    const float T = L6[0] + L6[1];             // 16-leaf subtree sum = pathnew_5[lane]

    if (lane < 32) {
#pragma unroll
      for (int i = 0; i < 16; ++i) { a19[i] += w[i];  a29[i] += b2f(j9.u[i]) * w[i]; }
#pragma unroll
      for (int i = 0; i < 8; ++i)  { a18[i] += L8[i]; a28[i] += b2f(j8.u[i]) * L8[i]; }
#pragma unroll
      for (int i = 0; i < 4; ++i)  { a17[i] += L7[i]; a27[i] += b2f(j7.u[i]) * L7[i]; }
#pragma unroll
      for (int i = 0; i < 2; ++i)  { a16[i] += L6[i]; a26[i] += b2f(j6.u[i]) * L6[i]; }
    }

    // layers 5..0: T subtree-sum tree (register data -> must stay shfl; 10 DS ops)
    const float T1 = T  + __shfl_xor(T, 1);    // pathnew_4 at even lanes
    const float T2 = T1 + __shfl_xor(T1, 2);   // pathnew_3 at lanes 4j
    const float T3 = T2 + __shfl_xor(T2, 4);   // pathnew_2 at lanes 8j
    const float T4 = T3 + __shfl_xor(T3, 8);   // pathnew_1 at lanes 16j
    const float T5 = T4 + __shfl_xor(T4, 16);  // pathnew_0[0] at lane 0
    const float v4 = __shfl(T1, (2 * lane) & 63);
    const float v3 = __shfl(T2, (4 * lane) & 63);
    const float v2 = __shfl(T3, (8 * lane) & 63);
    const float v1 = __shfl(T4, (16 * lane) & 63);
    const float v0 = __shfl(T5, 0);
    if (lane < 32) { t1[5] += T;  t2[5] += q5 * T; }
    if (lane < 16) { t1[4] += v4; t2[4] += q4 * v4; }
    if (lane < 8)  { t1[3] += v3; t2[3] += q3 * v3; }
    if (lane < 4)  { t1[2] += v2; t2[2] += q2 * v2; }
    if (lane < 2)  { t1[1] += v1; t2[1] += q1 * v1; }
    if (lane < 1)  { t1[0] += v0; t2[0] += q0 * v0; }
  }

  // merge register accumulators -> LDS (node id = 2^ell - 1 + j; S2 at +1024)
  if (lane < 32) {
#pragma unroll
    for (int i = 0; i < 16; ++i) { atomicAdd(&Ss[511 + 16 * la + i], a19[i]); atomicAdd(&Ss[1535 + 16 * la + i], a29[i]); }
#pragma unroll
    for (int i = 0; i < 8; ++i)  { atomicAdd(&Ss[255 + 8 * la + i],  a18[i]); atomicAdd(&Ss[1279 + 8 * la + i],  a28[i]); }
#pragma unroll
    for (int i = 0; i < 4; ++i)  { atomicAdd(&Ss[127 + 4 * la + i],  a17[i]); atomicAdd(&Ss[1151 + 4 * la + i],  a27[i]); }
#pragma unroll
    for (int i = 0; i < 2; ++i)  { atomicAdd(&Ss[63 + 2 * la + i],   a16[i]); atomicAdd(&Ss[1087 + 2 * la + i],  a26[i]); }
    atomicAdd(&Ss[31 + la], t1[5]); atomicAdd(&Ss[1055 + la], t2[5]);
    if (la < 16) { atomicAdd(&Ss[15 + la], t1[4]); atomicAdd(&Ss[1039 + la], t2[4]); }
    if (la < 8)  { atomicAdd(&Ss[7 + la],  t1[3]); atomicAdd(&Ss[1031 + la], t2[3]); }
    if (la < 4)  { atomicAdd(&Ss[3 + la],  t1[2]); atomicAdd(&Ss[1027 + la], t2[2]); }
    if (la < 2)  { atomicAdd(&Ss[1 + la],  t1[1]); atomicAdd(&Ss[1025 + la], t2[1]); }
    if (la < 1)  { atomicAdd(&Ss[0],       t1[0]); atomicAdd(&Ss[1024],      t2[0]); }
  }
  __syncthreads();
  // coalesced 8KB partial store into DEAD Xb region -- no aliasing with live data
  float* Sp = Spart + (size_t)blockIdx.x * 2048;
  for (int i = threadIdx.x; i < 2048; i += 256) Sp[i] = Ss[i];
}

// ---------------- reduce partials -> Sg -> regularizer (fused; last block finalizes) ----------------
__global__ __launch_bounds__(256) void reduce_fin(const float* __restrict__ Spart,
                                                  float* __restrict__ Sg,
                                                  float* __restrict__ outreg,
                                                  unsigned* __restrict__ ticket) {
  const int t = threadIdx.x;
  float acc[8] = {};
  const float* base = Spart + (size_t)blockIdx.x * 32 * 2048;
  for (int b = 0; b < 32; ++b) {
    const float* p = base + (size_t)b * 2048;
#pragma unroll
    for (int k = 0; k < 8; ++k) acc[k] += p[t + 256 * k];
  }
#pragma unroll
  for (int k = 0; k < 8; ++k) {
    const int i = t + 256 * k;
    const int node = i & 1023;
    if (node < 1023) atomicAdd(&Sg[(i < 1024 ? 0 : 2048) + node], acc[k]);
  }
  // ticket: last arriving block computes the regularizer (saves a dispatch)
  __threadfence();                               // my Sg atomics ordered before ticket
  __syncthreads();
  __shared__ unsigned rank;
  if (t == 0) rank = atomicAdd(ticket, 1u);
  __syncthreads();
  if (rank == 31) {
    double val = 0.0;
    for (int n = t; n < 1023; n += 256) {
      const int ell = 31 - __clz(n + 1);
      const double s1 = (double)__hip_atomic_load(&Sg[n], __ATOMIC_RELAXED, __HIP_MEMORY_SCOPE_AGENT);
      const double s2 = (double)__hip_atomic_load(&Sg[2048 + n], __ATOMIC_RELAXED, __HIP_MEMORY_SCOPE_AGENT);
      const double den = s1 + 1e-8;
      const double a0 = s2 / den;
      const double a1 = (s1 - s2) / den;
      const double f = 1e-3 * (1.0 / (double)(1 << ell));
      val += -0.5 * f * (log(a0) + log(1.0 - a0) + log(a1) + log(1.0 - a1));
    }
#pragma unroll
    for (int o = 32; o > 0; o >>= 1) val += __shfl_down(val, o, 64);
    __shared__ double partd[4];
    if ((t & 63) == 0) partd[t >> 6] = val;
    __syncthreads();
    if (t == 0) outreg[0] = (float)(partd[0] + partd[1] + partd[2] + partd[3]);
  }
}

extern "C" void kernel_launch(void* const* d_in, const int* in_sizes, int n_in,
                              void* d_out, int out_size, void* d_ws, size_t ws_size,
                              hipStream_t stream) {
  const float* X     = (const float*)d_in[0];   // [16384,1024]
  const float* Wint  = (const float*)d_in[1];   // [1023,1025]
  const float* Wleaf = (const float*)d_in[2];   // [1000,1024]
  float* out = (float*)d_out;                   // [16384*1000] preds + [1] reg
  char* ws = (char*)d_ws;                       // needs ~105 MB

  ushort* Xb   = (ushort*)(ws + OFF_XB);
  ushort* W1   = (ushort*)(ws + OFF_W1);
  float*  bias = (float*)(ws + OFF_BIAS);
  ushort* prob = (ushort*)(ws + OFF_PROB);
  ushort* path = (ushort*)(ws + OFF_PATH);
  ushort* W2   = (ushort*)(ws + OFF_W2);
  float*  Sg   = (float*)(ws + OFF_SG);
  unsigned* tkt = (unsigned*)(ws + OFF_TKT);
  float*  Spart = (float*)(ws + OFF_XB);        // Xb is dead after gemm<0>

  cvt_all<<<24577, 256, 0, stream>>>((const float4*)X, (ushort4*)Xb,
                                     Wint, Wleaf, W1, W2, bias, Sg, tkt);
  gemm_bt<0><<<dim3(128, 8), 256, 0, stream>>>(Xb, W1, bias, (void*)prob);
  tree_kernel<<<1024, 256, 0, stream>>>(prob, path, Spart);
  gemm_bt<1><<<dim3(128, 8), 256, 0, stream>>>(path, W2, nullptr, (void*)out);
  reduce_fin<<<32, 256, 0, stream>>>(Spart, Sg, out + (size_t)B_ROWS * N_OUT, tkt);
}